// Round 7
// baseline (281.076 us; speedup 1.0000x reference)
//
#include <hip/hip_runtime.h>
#include <stdint.h>

typedef unsigned long long u64;
typedef unsigned int u32;
typedef unsigned short u16;
typedef __attribute__((ext_vector_type(8))) short bf16x8;
typedef __attribute__((ext_vector_type(4))) float f32x4;

#define DD 128          // node_dim
#define EAD 16          // edge_attr dim
#define R2C 272.25f     // RADIUS^2
#define NBINS 4096
#define CAPB 16         // per-(center,block) candidate capacity
#define CANDCAP 512     // per-center collected-candidate capacity in K2
#define THRESHV 0.1
#define BN 128          // nodes per K1 block

// ---------------- workspace layout (bytes) ----------------
#define NPAD 100096
#define NBLKMAX 800
#define L32_BYTES ((size_t)256 * NBLKMAX * CAPB * 4)   // 13.1 MB
#define CNTB_OFF  L32_BYTES
#define CNTB_BYTES ((size_t)256 * NBLKMAX * 2)         // 400 KB
#define DBL_OFF   (CNTB_OFF + CNTB_BYTES)
// double indices within the double region:
#define DU    0                   // [128]  W_neigh @ lin_w
#define DR    128                 // [128]  W_root  @ lin_w
#define DV    256                 // [16]   W_edge  @ lin_w
#define DCC   272                 // [256]  per-center |c|^2 (fp64)
#define DROOT 528                 // [NPAD] x . r
#define DA    (528 + NPAD)        // [NPAD] x . u
#define DAGG  (528 + 2*NPAD)      // [NPAD] aggregate (zeroed)
#define DEND  (528 + 3*NPAD)
#define INT_OFF (DBL_OFF + (size_t)DEND * 8)
#define CCT_B   0                 // float2[256] (ccf, T)
#define MASK_B  2048              // u32[3200] in_nb bitmask (zeroed)
#define HNB_B   (2048 + 12800)    // int[256] has_neighbor (zeroed)
#define OVF_B   (2048 + 12800 + 1024) // u32[256] overflow flags (zeroed)
#define INT_BYTES (2048 + 12800 + 1024 + 1024)
#define BF_OFF   (INT_OFF + INT_BYTES)              // chi_sw + clo_sw (frag-ordered bf16)
#define ZERO_OFF   (DBL_OFF + (size_t)DAGG * 8)
#define ZERO_BYTES ((size_t)NPAD * 8 + INT_BYTES)   // agg64 + cct + mask + hnb + ovf
#define WS_NEED    (BF_OFF + 2*(size_t)256*128*2)

__device__ __forceinline__ float fma4(float4 a, float4 b, float acc) {
  acc = fmaf(a.x, b.x, acc); acc = fmaf(a.y, b.y, acc);
  acc = fmaf(a.z, b.z, acc); acc = fmaf(a.w, b.w, acc);
  return acc;
}

// round-to-nearest-even f32 -> bf16 (finite inputs)
__device__ __forceinline__ short f2bf(float f) {
  u32 u = __float_as_uint(f);
  u32 r = (u + 0x7fffu + ((u >> 16) & 1u)) >> 16;
  return (short)r;
}
__device__ __forceinline__ float bf2f(short h) {
  return __uint_as_float(((u32)(unsigned short)h) << 16);
}

// fp32 d2 (fallback path only; self-consistent within K2)
__device__ float d2f32(const float* __restrict__ center, const float* __restrict__ x,
                       int c, int n, float ccv) {
  float dt = 0.f, xx = 0.f;
  for (int j = 0; j < DD; j += 4) {
    float4 xv = *(const float4*)(x + (size_t)n*DD + j);
    float4 cv = *(const float4*)(center + (size_t)c*DD + j);
    dt = fma4(xv, cv, dt); xx = fma4(xv, xv, xx);
  }
  return (ccv + xx) - 2.0f*dt;
}

// ---------- KA: wave-per-row precompute ----------
// waves 0..127   : u[row], r[row] (fp64 dots of Wn/Wr rows with lw)
// waves 128..143 : v[k] (We rows)
// waves 144..399 : per-center cc (fp64), cct=(ccf,T), frag-ordered bf16 hi/lo split
__global__ void ka_pre(const float* __restrict__ Wr, const float* __restrict__ Wn,
                       const float* __restrict__ We, const float* __restrict__ lw,
                       const float* __restrict__ center,
                       double* __restrict__ dbl, float2* __restrict__ cct,
                       short* __restrict__ chi_sw, short* __restrict__ clo_sw) {
  const int gw = blockIdx.x * 4 + (threadIdx.x >> 6);
  const int lane = threadIdx.x & 63;
  const int j0 = lane * 2;

  if (gw < 128) {
    const int row = gw;
    float2 wn2 = *(const float2*)(Wn + (size_t)row*DD + j0);
    float2 wr2 = *(const float2*)(Wr + (size_t)row*DD + j0);
    float2 lw2 = *(const float2*)(lw + j0);
    double su = fma((double)wn2.x, (double)lw2.x, (double)wn2.y * (double)lw2.y);
    double sr = fma((double)wr2.x, (double)lw2.x, (double)wr2.y * (double)lw2.y);
    #pragma unroll
    for (int off = 32; off; off >>= 1) {
      su += __shfl_xor(su, off, 64);
      sr += __shfl_xor(sr, off, 64);
    }
    if (lane == 0) { dbl[DU + row] = su; dbl[DR + row] = sr; }
  } else if (gw < 144) {
    const int k = gw - 128;
    float2 we2 = *(const float2*)(We + (size_t)k*DD + j0);
    float2 lw2 = *(const float2*)(lw + j0);
    double sv = fma((double)we2.x, (double)lw2.x, (double)we2.y * (double)lw2.y);
    #pragma unroll
    for (int off = 32; off; off >>= 1) sv += __shfl_xor(sv, off, 64);
    if (lane == 0) dbl[DV + k] = sv;
  } else if (gw < 400) {
    const int c = gw - 144;
    const int cblk = c >> 4, r16c = c & 15;
    float2 cv2 = *(const float2*)(center + (size_t)c*DD + j0);
    double s = fma((double)cv2.x, (double)cv2.x, (double)cv2.y * (double)cv2.y);
    const float* pc = (const float*)&cv2;
    #pragma unroll
    for (int t = 0; t < 2; ++t) {
      const int j = j0 + t;
      const int kc = j >> 5, kg = (j >> 3) & 3, e = j & 7;
      const int idx = (((cblk*4 + kc)*64) + kg*16 + r16c)*8 + e;
      short h = f2bf(pc[t]);
      chi_sw[idx] = h;
      clo_sw[idx] = f2bf(pc[t] - bf2f(h));
    }
    #pragma unroll
    for (int off = 32; off; off >>= 1) s += __shfl_xor(s, off, 64);
    if (lane == 0) {
      dbl[DCC + c] = s;
      float ccf = (float)s;
      // candidate threshold: mean cc+D, sd=sqrt(2D+4cc); z=2.25 -> ~1200 candidates,
      // far above the top-64 cutoff; K2 fallback covers any miss
      float T = ccf + (float)DD - 2.25f * sqrtf(2.0f*(float)DD + 4.0f*ccf);
      T = fminf(T, R2C);
      cct[c] = make_float2(ccf, T);
    }
  }
}

// ---------- K1: fused (node scalars + bf16-split MFMA + LDS-aggregated capture) ----------
// x LDS tile 16B-slot address: row-stride 64B, slot XOR-swizzle -> conflict-free b128.
__device__ __forceinline__ int a16(int row, int kg) {
  return row*32 + (((kg ^ (row >> 1)) & 3) << 3);   // element (short) index
}

__launch_bounds__(512, 4)
__global__ void k1_mfma(const float* __restrict__ x,
                        const short* __restrict__ chi_sw, const short* __restrict__ clo_sw,
                        const float2* __restrict__ cct, const double* __restrict__ dbl,
                        double* __restrict__ root64, double* __restrict__ a64,
                        u32* __restrict__ list32, u16* __restrict__ cntb,
                        u32* __restrict__ ovf, int N, int NBLK) {
  __shared__ __align__(16) short xsh[2][2][128*32];  // [dbuf][hi/lo] 8KB each = 32 KB
  __shared__ float2 scct[256];                       // 2 KB
  __shared__ float sxx[128];                         // 0.5 KB
  __shared__ u32 cap_cnt[256];                       // 1 KB
  __shared__ u32 cap_buf[256*CAPB];                  // 16 KB

  const int tid = threadIdx.x;
  const int blk = blockIdx.x;
  const int bn  = blk * BN;
  const int wid = tid >> 6, l = tid & 63, r16 = l & 15, kg = l >> 4;
  const int wc = wid >> 1, wn = wid & 1;             // 4 center-strips x 2 node-strips

  if (tid < 256) { scct[tid] = cct[tid]; cap_cnt[tid] = 0u; }

  const int srow = tid >> 2, sq = tid & 3;           // staging: 4 threads per node row
  const int sgn  = bn + srow;
  const bool sok = (sgn < N);

  f32x4 acc[4][4];
  #pragma unroll
  for (int tc = 0; tc < 4; ++tc)
    #pragma unroll
    for (int tn = 0; tn < 4; ++tn) acc[tc][tn] = (f32x4){0.f,0.f,0.f,0.f};

  float4 v0 = make_float4(0.f,0.f,0.f,0.f), v1 = v0;
  if (sok) {
    v0 = *(const float4*)(x + (size_t)sgn*DD + sq*8);
    v1 = *(const float4*)(x + (size_t)sgn*DD + sq*8 + 4);
  }

  float xxp = 0.f; double rap = 0.0, aap = 0.0;

  for (int kc = 0; kc < 4; ++kc) {
    // convert current chunk, write LDS (buffer kc&1)
    union { short s[8]; bf16x8 v; } hi, lo;
    const float* p0 = (const float*)&v0; const float* p1 = (const float*)&v1;
    #pragma unroll
    for (int q = 0; q < 4; ++q) {
      short h0 = f2bf(p0[q]); hi.s[q]   = h0; lo.s[q]   = f2bf(p0[q] - bf2f(h0));
      short h1 = f2bf(p1[q]); hi.s[q+4] = h1; lo.s[q+4] = f2bf(p1[q] - bf2f(h1));
    }
    short* xh = &xsh[kc & 1][0][0];
    short* xl = &xsh[kc & 1][1][0];
    *(bf16x8*)&xh[a16(srow, sq)] = hi.v;
    *(bf16x8*)&xl[a16(srow, sq)] = lo.v;

    // per-node scalar partials (xx fp32; root/a fp64 vs dbl[], L1/L2-hot)
    #pragma unroll
    for (int q = 0; q < 4; ++q) {
      xxp = fmaf(p0[q], p0[q], xxp); xxp = fmaf(p1[q], p1[q], xxp);
      double d0 = (double)p0[q], d1 = (double)p1[q];
      const int jb = kc*32 + sq*8 + q;
      rap = fma(d0, dbl[DR + jb], rap);     aap = fma(d0, dbl[DU + jb], aap);
      rap = fma(d1, dbl[DR + jb + 4], rap); aap = fma(d1, dbl[DU + jb + 4], aap);
    }

    // prefetch next x chunk (in flight across barrier + MFMA)
    if (kc < 3 && sok) {
      v0 = *(const float4*)(x + (size_t)sgn*DD + (kc+1)*32 + sq*8);
      v1 = *(const float4*)(x + (size_t)sgn*DD + (kc+1)*32 + sq*8 + 4);
    }

    // a-frags: direct from L2-resident frag-ordered global (1KB/wave, coalesced)
    bf16x8 ah[4], al[4];
    #pragma unroll
    for (int tc = 0; tc < 4; ++tc) {
      const int cblk = wc*4 + tc;
      const size_t off = (size_t)(((cblk*4 + kc)*64) + l) * 8;
      ah[tc] = *(const bf16x8*)(chi_sw + off);
      al[tc] = *(const bf16x8*)(clo_sw + off);
    }

    __syncthreads();   // staging of buf kc&1 visible; prior-buffer reads all done

    #pragma unroll
    for (int tn = 0; tn < 4; ++tn) {
      const int rn = wn*64 + tn*16 + r16;
      bf16x8 bh = *(bf16x8*)&xh[a16(rn, kg)];
      bf16x8 bl = *(bf16x8*)&xl[a16(rn, kg)];
      #pragma unroll
      for (int tc = 0; tc < 4; ++tc) {
        acc[tc][tn] = __builtin_amdgcn_mfma_f32_16x16x32_bf16(ah[tc], bh, acc[tc][tn], 0,0,0);
        acc[tc][tn] = __builtin_amdgcn_mfma_f32_16x16x32_bf16(ah[tc], bl, acc[tc][tn], 0,0,0);
        acc[tc][tn] = __builtin_amdgcn_mfma_f32_16x16x32_bf16(al[tc], bh, acc[tc][tn], 0,0,0);
      }
    }
  }

  // reduce per-node scalars across the 4 staging lanes (bits 0..1 of lane)
  xxp += __shfl_xor(xxp, 1, 64); xxp += __shfl_xor(xxp, 2, 64);
  rap += __shfl_xor(rap, 1, 64); rap += __shfl_xor(rap, 2, 64);
  aap += __shfl_xor(aap, 1, 64); aap += __shfl_xor(aap, 2, 64);
  if (sq == 0) {
    sxx[srow] = xxp;
    if (sok) { root64[sgn] = rap; a64[sgn] = aap; }
  }
  __syncthreads();

  // capture into LDS (no global atomics)
  const float bscale = (float)NBINS / R2C;
  #pragma unroll
  for (int tn = 0; tn < 4; ++tn) {
    const int ln = wn*64 + tn*16 + r16;
    const int gn = bn + ln;
    if (gn >= N) continue;
    const float xv = sxx[ln];
    #pragma unroll
    for (int tc = 0; tc < 4; ++tc) {
      #pragma unroll
      for (int q = 0; q < 4; ++q) {
        const int c = wc*64 + tc*16 + kg*4 + q;
        const float2 ct = scct[c];
        const float val = (ct.x + xv) - 2.0f * acc[tc][tn][q];
        if (val <= ct.y) {
          int b = (int)(val * bscale); b = min(NBINS-1, max(0, b));
          u32 slot = atomicAdd(&cap_cnt[c], 1u);
          if (slot < CAPB) cap_buf[c*CAPB + slot] = ((u32)b << 17) | (u32)gn;
        }
      }
    }
  }
  __syncthreads();

  // deterministic write-out (no contention)
  if (tid < 256) {
    u32 cc = cap_cnt[tid];
    if (cc > CAPB) { atomicOr(&ovf[tid], 1u); cc = CAPB; }
    cntb[(size_t)tid*NBLK + blk] = (u16)cc;
  }
  for (int i = tid; i < 256*CAPB; i += 512) {
    const int c = i >> 4, j = i & (CAPB-1);
    list32[((size_t)c*NBLK + blk)*CAPB + j] = cap_buf[i];
  }
}

// ---------- K2: exact per-center top-64 (fp64 re-rank of candidates) ----------
__launch_bounds__(256)
__global__ void k2_sel(const float* __restrict__ x, const float* __restrict__ center,
                       const double* __restrict__ dbl, const float2* __restrict__ cct,
                       u32* __restrict__ mask, int* __restrict__ hnb,
                       const u32* __restrict__ list32, const u16* __restrict__ cntb,
                       const u32* __restrict__ ovf, int N, int NBLK) {
  const int c = blockIdx.x, tid = threadIdx.x;
  __shared__ u32 hist[NBINS];
  __shared__ double dval[CANDCAP];
  __shared__ int    dnode[CANDCAP];
  __shared__ u32 spart[256];
  __shared__ int shW, shB, shQ;

  for (int i = tid; i < NBINS; i += 256) hist[i] = 0u;
  if (tid == 0) { shW = 0; shB = 0x7ffffff; shQ = 0; }
  __syncthreads();

  const float2 ct = cct[c];
  const bool ovfc = (ovf[c] != 0u);
  const float bscale = (float)NBINS / R2C;

  if (!ovfc) {
    int csum = 0;
    for (int blk = tid; blk < NBLK; blk += 256) {
      const int cc = cntb[(size_t)c*NBLK + blk];
      csum += cc;
      const size_t base = ((size_t)c*NBLK + blk)*CAPB;
      for (int j = 0; j < cc; ++j) atomicAdd(&hist[list32[base + j] >> 17], 1u);
    }
    atomicAdd(&shW, csum);
  }
  __syncthreads();
  int C = shW;
  const bool fast = !ovfc && (C >= 64);

  if (!fast) {
    // exact fallback: full fp32 rescan of this center's row
    for (int i = tid; i < NBINS; i += 256) hist[i] = 0u;
    if (tid == 0) shW = 0;
    __syncthreads();
    int w = 0;
    for (int n = tid; n < N; n += 256) {
      float val = d2f32(center, x, c, n, ct.x);
      if (val <= R2C) {
        ++w;
        int b = (int)(val * bscale); b = min(NBINS-1, max(0, b));
        atomicAdd(&hist[b], 1u);
      }
    }
    atomicAdd(&shW, w);
    __syncthreads();
    C = shW;
    if (C == 0) return;                // has_nb stays 0
  }
  const int Rk = min(64, C);

  // block-wide scan of hist -> first bin B with cum >= Rk
  u32 loc[16]; u32 psum = 0;
  const int b0 = tid * 16;
  #pragma unroll
  for (int k = 0; k < 16; ++k) { loc[k] = hist[b0 + k]; psum += loc[k]; }
  spart[tid] = psum; __syncthreads();
  for (int off = 1; off < 256; off <<= 1) {
    u32 vv = (tid >= off) ? spart[tid - off] : 0u;
    __syncthreads(); spart[tid] += vv; __syncthreads();
  }
  u32 run = spart[tid] - psum;
  int Bl = 0x7ffffff;
  #pragma unroll
  for (int k = 0; k < 16; ++k) { run += loc[k]; if ((int)run >= Rk && Bl == 0x7ffffff) Bl = b0 + k; }
  if (Bl != 0x7ffffff) atomicMin(&shB, Bl);
  __syncthreads();
  const int Bcol = min(shB + 2, NBINS - 1);  // +2 bins slack >> bf16-split/fp32 noise

  // collect candidate nodes with bin <= Bcol
  if (fast) {
    for (int blk = tid; blk < NBLK; blk += 256) {
      const int cc = cntb[(size_t)c*NBLK + blk];
      const size_t base = ((size_t)c*NBLK + blk)*CAPB;
      for (int j = 0; j < cc; ++j) {
        const u32 e = list32[base + j];
        if ((int)(e >> 17) <= Bcol) {
          int s = atomicAdd(&shQ, 1);
          if (s < CANDCAP) dnode[s] = (int)(e & 0x1FFFFu);
        }
      }
    }
  } else {
    for (int n = tid; n < N; n += 256) {
      float val = d2f32(center, x, c, n, ct.x);
      if (val <= R2C) {
        int b = (int)(val * bscale); b = min(NBINS-1, max(0, b));
        if (b <= Bcol) { int s = atomicAdd(&shQ, 1); if (s < CANDCAP) dnode[s] = n; }
      }
    }
  }
  __syncthreads();
  const int Q = min(shQ, CANDCAP);

  // fp64 re-rank (unrolled: independent load batches, 2 accumulator pairs)
  const double ccd = dbl[DCC + c];
  for (int i = tid; i < Q; i += 256) {
    const int n = dnode[i];
    const float4* xp = (const float4*)(x + (size_t)n*DD);
    const float4* cp = (const float4*)(center + (size_t)c*DD);
    double dt0 = 0.0, dt1 = 0.0, xx0 = 0.0, xx1 = 0.0;
    #pragma unroll 8
    for (int j = 0; j < 32; j += 2) {
      float4 a0 = xp[j],   b0f = cp[j];
      float4 a1 = xp[j+1], b1f = cp[j+1];
      const float* pa0 = (const float*)&a0; const float* pb0 = (const float*)&b0f;
      const float* pa1 = (const float*)&a1; const float* pb1 = (const float*)&b1f;
      #pragma unroll
      for (int q = 0; q < 4; ++q) {
        double da0 = (double)pa0[q], db0 = (double)pb0[q];
        double da1 = (double)pa1[q], db1 = (double)pb1[q];
        dt0 = fma(da0, db0, dt0); xx0 = fma(da0, da0, xx0);
        dt1 = fma(da1, db1, dt1); xx1 = fma(da1, da1, xx1);
      }
    }
    dval[i] = (ccd + (xx0 + xx1)) - 2.0*(dt0 + dt1);
  }
  __syncthreads();

  // exact rank-select: keep rank < Rk under (val, node) lexicographic order
  for (int i = tid; i < Q; i += 256) {
    double vi = dval[i]; int ni = dnode[i];
    int rank = 0;
    for (int j = 0; j < Q; ++j) {
      double vj = dval[j];
      rank += (vj < vi) || (vj == vi && dnode[j] < ni);
    }
    if (rank < Rk) atomicOr(&mask[(u32)ni >> 5], 1u << (ni & 31));
  }
  if (tid == 0) hnb[c] = 1;
}

// ---------- K3: edge pass (fp64 scalar messages, edge_attr read only when kept) ----------
__global__ void k3_edge(const int* __restrict__ ei, const float* __restrict__ eattr,
                        const double* __restrict__ dbl, const u32* __restrict__ mask,
                        double* __restrict__ agg, const double* __restrict__ a64, int E) {
  int e = blockIdx.x*256 + threadIdx.x;
  if (e >= E) return;
  int s = ei[e], d = ei[E + e];
  u32 ks = (mask[(u32)s >> 5] >> (s & 31)) & 1u;
  u32 kd = (mask[(u32)d >> 5] >> (d & 31)) & 1u;
  if (!(ks & kd)) return;
  const float* ep = eattr + (size_t)e * EAD;
  double ea = 0.0;
  #pragma unroll
  for (int k = 0; k < EAD; ++k) ea = fma((double)ep[k], dbl[DV + k], ea);
  atomicAdd(&agg[d], a64[s] + ea);
}

// ---------- K4: gate + int32 output ----------
__global__ void k4_out(const double* __restrict__ root64, const double* __restrict__ agg64,
                       const u32* __restrict__ mask, const int* __restrict__ hnb,
                       const float* __restrict__ lb, int* __restrict__ out, int N, int M) {
  int n = blockIdx.x*256 + threadIdx.x;
  if (n >= N) return;
  double pre = root64[n] + agg64[n] + (double)lb[0];
  bool selb = ((mask[n >> 5] >> (n & 31)) & 1u) != 0u;
  if (!selb && n < M) selb = hnb[n] != 0;
  out[n] = (selb && pre > THRESHV) ? 1 : 0;
}

extern "C" void kernel_launch(void* const* d_in, const int* in_sizes, int n_in,
                              void* d_out, int out_size, void* d_ws, size_t ws_size,
                              hipStream_t stream) {
  const float* x      = (const float*)d_in[0];
  const int*   ei     = (const int*)d_in[1];
  const float* eattr  = (const float*)d_in[2];
  const float* center = (const float*)d_in[3];
  const float* Wr     = (const float*)d_in[4];
  const float* Wn     = (const float*)d_in[5];
  const float* We     = (const float*)d_in[6];
  const float* lw     = (const float*)d_in[7];
  const float* lb     = (const float*)d_in[8];
  int* out = (int*)d_out;

  char* wsb = (char*)d_ws;
  u32*    list32 = (u32*)(wsb);
  u16*    cntb   = (u16*)(wsb + CNTB_OFF);
  double* dbl    = (double*)(wsb + DBL_OFF);
  float2* cct    = (float2*)(wsb + INT_OFF + CCT_B);
  u32*    mask   = (u32*)(wsb + INT_OFF + MASK_B);
  int*    hnb    = (int*)(wsb + INT_OFF + HNB_B);
  u32*    ovf    = (u32*)(wsb + INT_OFF + OVF_B);
  short*  chi_sw = (short*)(wsb + BF_OFF);
  short*  clo_sw = chi_sw + (size_t)256*DD;
  double* root64 = dbl + DROOT;
  double* a64    = dbl + DA;
  double* agg64  = dbl + DAGG;

  const int N = in_sizes[0] / DD;      // 100000
  const int E = in_sizes[1] / 2;       // 1000000
  const int M = in_sizes[3] / DD;      // 256
  const int NBLK = (N + BN - 1) / BN;  // 782
  if (N > NPAD || M != 256 || NBLK > NBLKMAX || ws_size < WS_NEED) return;
  (void)n_in; (void)out_size;

  // zero agg64 + cct + mask + hnb + ovf (contiguous; cct rewritten by ka_pre);
  // cntb needs no init (written unconditionally by k1 for all blk < NBLK)
  hipMemsetAsync(wsb + ZERO_OFF, 0, ZERO_BYTES, stream);

  ka_pre<<<100, 256, 0, stream>>>(Wr, Wn, We, lw, center, dbl, cct, chi_sw, clo_sw);
  k1_mfma<<<NBLK, 512, 0, stream>>>(x, chi_sw, clo_sw, cct, dbl, root64, a64,
                                    list32, cntb, ovf, N, NBLK);
  k2_sel<<<M, 256, 0, stream>>>(x, center, dbl, cct, mask, hnb, list32, cntb, ovf, N, NBLK);
  k3_edge<<<(E + 255)/256, 256, 0, stream>>>(ei, eattr, dbl, mask, agg64, a64, E);
  k4_out<<<(N + 255)/256, 256, 0, stream>>>(root64, agg64, mask, hnb, lb, out, N, M);
}